// Round 1
// baseline (143.311 us; speedup 1.0000x reference)
//
#include <hip/hip_runtime.h>

#define HM_B 32
#define HM_C 98
#define HM_H 128
#define HM_W 128
#define HWSZ (HM_H * HM_W)          // 16384
#define FDIM 256
#define DDIM 128
#define NODE_F (2 + 1 + FDIM)       // 259
#define BC (HM_B * HM_C)            // 3136
#define HM_ELEMS ((size_t)BC * HWSZ)

// Kernel 1: copy hm -> d_out while computing per-(b,c) argmax (first-occurrence)
__global__ __launch_bounds__(256) void argmax_copy_kernel(
    const float* __restrict__ hm, float* __restrict__ out_hm,
    int* __restrict__ idx_ws, float* __restrict__ conf_ws) {
    const int bc = blockIdx.x;
    const int tid = threadIdx.x;
    const float4* __restrict__ src = (const float4*)(hm + (size_t)bc * HWSZ);
    float4* __restrict__ dst = (float4*)(out_hm + (size_t)bc * HWSZ);

    float bv = -INFINITY;
    int bi = 0;
    // 16384 floats = 4096 float4, 256 threads -> 16 iters; indices ascend per
    // thread, so strict '>' keeps first occurrence within a thread.
    #pragma unroll
    for (int t = 0; t < HWSZ / 4 / 256; ++t) {
        const int p = t * 256 + tid;
        const float4 v = src[p];
        dst[p] = v;
        const int base = p * 4;
        if (v.x > bv) { bv = v.x; bi = base; }
        if (v.y > bv) { bv = v.y; bi = base + 1; }
        if (v.z > bv) { bv = v.z; bi = base + 2; }
        if (v.w > bv) { bv = v.w; bi = base + 3; }
    }

    __shared__ float sv[256];
    __shared__ int si[256];
    sv[tid] = bv; si[tid] = bi;
    __syncthreads();
    for (int s = 128; s > 0; s >>= 1) {
        if (tid < s) {
            const float ov = sv[tid + s];
            const int oi = si[tid + s];
            if (ov > sv[tid] || (ov == sv[tid] && oi < si[tid])) {
                sv[tid] = ov; si[tid] = oi;
            }
        }
        __syncthreads();
    }
    if (tid == 0) { idx_ws[bc] = si[0]; conf_ws[bc] = sv[0]; }
}

// Kernel 2: gather vis features, build node vector, h0 = relu(node @ W_embed + b)
__global__ __launch_bounds__(128) void embed_kernel(
    const float* __restrict__ feat, const int* __restrict__ idx_ws,
    const float* __restrict__ conf_ws, const float* __restrict__ W_embed,
    const float* __restrict__ b_embed, float* __restrict__ h0) {
    const int bc = blockIdx.x;
    const int b = bc / HM_C;
    const int tid = threadIdx.x;
    __shared__ float node[NODE_F];

    const int loc = idx_ws[bc];
    node[3 + tid]       = feat[((size_t)(b * FDIM + tid)) * HWSZ + loc];
    node[3 + 128 + tid] = feat[((size_t)(b * FDIM + 128 + tid)) * HWSZ + loc];
    if (tid == 0) {
        const int ys = loc / HM_W;
        const int xs = loc % HM_W;
        // reference: pos = [xs, ys] / [H, W]
        node[0] = (float)xs / (float)HM_H;
        node[1] = (float)ys / (float)HM_W;
        node[2] = conf_ws[bc];
    }
    __syncthreads();

    float acc = b_embed[tid];
    #pragma unroll 7
    for (int f = 0; f < NODE_F; ++f)
        acc = fmaf(node[f], W_embed[f * DDIM + tid], acc);
    h0[(size_t)bc * DDIM + tid] = fmaxf(acc, 0.f);
}

// Kernel 3a: tmp[b,i,:] = sum_j A[i,j] * h0[b,j,:]
__global__ __launch_bounds__(128) void gcn_a_kernel(
    const float* __restrict__ A, const float* __restrict__ h0,
    float* __restrict__ tmp) {
    const int bc = blockIdx.x;
    const int b = bc / HM_C;
    const int i = bc % HM_C;
    const int tid = threadIdx.x;
    __shared__ float arow[HM_C];
    if (tid < HM_C) arow[tid] = A[i * HM_C + tid];
    __syncthreads();

    float acc = 0.f;
    #pragma unroll 7
    for (int j = 0; j < HM_C; ++j)
        acc = fmaf(arow[j], h0[((size_t)b * HM_C + j) * DDIM + tid], acc);
    tmp[(size_t)bc * DDIM + tid] = acc;
}

// Kernel 3b: h1 = relu(tmp @ W_gcn); out = h1 @ W_out + b_out
__global__ __launch_bounds__(128) void gcn_b_kernel(
    const float* __restrict__ tmp, const float* __restrict__ W_gcn,
    const float* __restrict__ W_out, const float* __restrict__ b_out,
    float* __restrict__ out2) {
    const int bc = blockIdx.x;
    const int tid = threadIdx.x;
    __shared__ float trow[DDIM];
    __shared__ float h1s[DDIM];
    trow[tid] = tmp[(size_t)bc * DDIM + tid];
    __syncthreads();

    float acc = 0.f;
    #pragma unroll 8
    for (int k = 0; k < DDIM; ++k)
        acc = fmaf(trow[k], W_gcn[k * DDIM + tid], acc);
    h1s[tid] = fmaxf(acc, 0.f);
    __syncthreads();

    if (tid < 2) {
        float o = b_out[tid];
        for (int d = 0; d < DDIM; ++d)
            o = fmaf(h1s[d], W_out[d * 2 + tid], o);
        out2[(size_t)bc * 2 + tid] = o;
    }
}

extern "C" void kernel_launch(void* const* d_in, const int* in_sizes, int n_in,
                              void* d_out, int out_size, void* d_ws, size_t ws_size,
                              hipStream_t stream) {
    const float* hm      = (const float*)d_in[0];
    const float* feat    = (const float*)d_in[1];
    const float* W_embed = (const float*)d_in[2];
    const float* b_embed = (const float*)d_in[3];
    const float* A       = (const float*)d_in[4];
    const float* W_gcn   = (const float*)d_in[5];
    const float* W_out   = (const float*)d_in[6];
    const float* b_out   = (const float*)d_in[7];

    float* out_hm = (float*)d_out;                 // [B,C,H,W] passthrough
    float* out2   = (float*)d_out + HM_ELEMS;      // [B,C,2]

    // workspace layout
    char* ws = (char*)d_ws;
    int*   idx_ws  = (int*)ws;                               ws += BC * sizeof(int);
    float* conf_ws = (float*)ws;                             ws += BC * sizeof(float);
    float* h0      = (float*)ws;                             ws += (size_t)BC * DDIM * sizeof(float);
    float* tmp     = (float*)ws;

    argmax_copy_kernel<<<BC, 256, 0, stream>>>(hm, out_hm, idx_ws, conf_ws);
    embed_kernel<<<BC, 128, 0, stream>>>(feat, idx_ws, conf_ws, W_embed, b_embed, h0);
    gcn_a_kernel<<<BC, 128, 0, stream>>>(A, h0, tmp);
    gcn_b_kernel<<<BC, 128, 0, stream>>>(tmp, W_gcn, W_out, b_out, out2);
}

// Round 2
// 128.450 us; speedup vs baseline: 1.1157x; 1.1157x over previous
//
#include <hip/hip_runtime.h>

#define HM_B 32
#define HM_C 98
#define HM_H 128
#define HM_W 128
#define HWSZ (HM_H * HM_W)          // 16384
#define FDIM 256
#define DDIM 128
#define NODE_F (2 + 1 + FDIM)       // 259
#define BC (HM_B * HM_C)            // 3136
#define HM_ELEMS ((size_t)BC * HWSZ)
#define LCHUNK 8                    // landmarks per embed block (3136/8 = 392)
#define ICHUNK 7                    // rows per gcn block (98 = 14*7)

typedef float f32x4 __attribute__((ext_vector_type(4)));

// Kernel 1: copy hm -> d_out while computing per-(b,c) argmax (first-occurrence)
__global__ __launch_bounds__(256) void argmax_copy_kernel(
    const float* __restrict__ hm, float* __restrict__ out_hm,
    int* __restrict__ idx_ws, float* __restrict__ conf_ws) {
    const int bc = blockIdx.x;
    const int tid = threadIdx.x;
    const f32x4* __restrict__ src = (const f32x4*)(hm + (size_t)bc * HWSZ);
    f32x4* __restrict__ dst = (f32x4*)(out_hm + (size_t)bc * HWSZ);

    float bv = -INFINITY;
    int bi = 0;
    #pragma unroll
    for (int t = 0; t < HWSZ / 4 / 256; ++t) {
        const int p = t * 256 + tid;
        const f32x4 v = __builtin_nontemporal_load(src + p);
        __builtin_nontemporal_store(v, dst + p);
        const float m4 = fmaxf(fmaxf(v[0], v[1]), fmaxf(v[2], v[3]));
        if (m4 > bv) {  // rare after warm-up; in-order keeps first occurrence
            const int base = p * 4;
            if (v[0] > bv) { bv = v[0]; bi = base; }
            if (v[1] > bv) { bv = v[1]; bi = base + 1; }
            if (v[2] > bv) { bv = v[2]; bi = base + 2; }
            if (v[3] > bv) { bv = v[3]; bi = base + 3; }
        }
    }

    __shared__ float sv[256];
    __shared__ int si[256];
    sv[tid] = bv; si[tid] = bi;
    __syncthreads();
    for (int s = 128; s > 0; s >>= 1) {
        if (tid < s) {
            const float ov = sv[tid + s];
            const int oi = si[tid + s];
            if (ov > sv[tid] || (ov == sv[tid] && oi < si[tid])) {
                sv[tid] = ov; si[tid] = oi;
            }
        }
        __syncthreads();
    }
    if (tid == 0) { idx_ws[bc] = si[0]; conf_ws[bc] = sv[0]; }
}

// Kernel 2: batched embed — 8 landmarks per block, W_embed read once per block.
// h0[bc, d] = relu(node[bc] . W_embed[:, d] + b_embed[d])
__global__ __launch_bounds__(256) void embed_kernel(
    const float* __restrict__ feat, const int* __restrict__ idx_ws,
    const float* __restrict__ conf_ws, const float* __restrict__ W_embed,
    const float* __restrict__ b_embed, float* __restrict__ h0) {
    const int bc0 = blockIdx.x * LCHUNK;
    const int tid = threadIdx.x;
    __shared__ float node_s[LCHUNK][NODE_F + 1];  // +1 pad

    if (tid < LCHUNK) {
        const int bcL = bc0 + tid;
        const int loc = idx_ws[bcL];
        const int ys = loc / HM_W;
        const int xs = loc % HM_W;
        node_s[tid][0] = (float)xs / (float)HM_H;   // reference: [xs,ys]/[H,W]
        node_s[tid][1] = (float)ys / (float)HM_W;
        node_s[tid][2] = conf_ws[bcL];
    }
    #pragma unroll
    for (int l = 0; l < LCHUNK; ++l) {
        const int bcL = bc0 + l;
        const int b = bcL / HM_C;
        const int loc = idx_ws[bcL];                 // wave-uniform, L2-hit
        node_s[l][3 + tid] = feat[((size_t)(b * FDIM + tid)) * HWSZ + loc];
    }
    __syncthreads();

    // 256 threads: d = tid & 127, half = tid >> 7 -> 4 landmarks each
    const int d = tid & (DDIM - 1);
    const int lbase = (tid >> 7) * 4;
    const float bias = b_embed[d];
    float acc0 = bias, acc1 = bias, acc2 = bias, acc3 = bias;
    for (int f = 0; f < NODE_F; ++f) {
        const float w = W_embed[f * DDIM + d];
        acc0 = fmaf(node_s[lbase + 0][f], w, acc0);
        acc1 = fmaf(node_s[lbase + 1][f], w, acc1);
        acc2 = fmaf(node_s[lbase + 2][f], w, acc2);
        acc3 = fmaf(node_s[lbase + 3][f], w, acc3);
    }
    h0[(size_t)(bc0 + lbase + 0) * DDIM + d] = fmaxf(acc0, 0.f);
    h0[(size_t)(bc0 + lbase + 1) * DDIM + d] = fmaxf(acc1, 0.f);
    h0[(size_t)(bc0 + lbase + 2) * DDIM + d] = fmaxf(acc2, 0.f);
    h0[(size_t)(bc0 + lbase + 3) * DDIM + d] = fmaxf(acc3, 0.f);
}

// Kernel 3: fused GCN. One block per (b, 7-row chunk). Stages h0[b] (50 KB)
// in LDS; tmp and h1 never leave the block.
__global__ __launch_bounds__(128) void gcn_kernel(
    const float* __restrict__ A, const float* __restrict__ h0,
    const float* __restrict__ W_gcn, const float* __restrict__ W_out,
    const float* __restrict__ b_out, float* __restrict__ out2) {
    const int b = blockIdx.x / (HM_C / ICHUNK);
    const int i0 = (blockIdx.x % (HM_C / ICHUNK)) * ICHUNK;
    const int tid = threadIdx.x;           // = d

    __shared__ float h0_s[HM_C * DDIM];    // 50176 B
    __shared__ float tmp_s[ICHUNK * DDIM]; // 3584 B
    __shared__ float h1_s[ICHUNK * DDIM];  // 3584 B

    for (int j = 0; j < HM_C; ++j)
        h0_s[j * DDIM + tid] = h0[((size_t)b * HM_C + j) * DDIM + tid];
    __syncthreads();

    // tmp[i,d] = sum_j A[i0+i, j] * h0[b, j, d]
    {
        float acc[ICHUNK];
        #pragma unroll
        for (int i = 0; i < ICHUNK; ++i) acc[i] = 0.f;
        for (int j = 0; j < HM_C; ++j) {
            const float v = h0_s[j * DDIM + tid];
            #pragma unroll
            for (int i = 0; i < ICHUNK; ++i)
                acc[i] = fmaf(A[(i0 + i) * HM_C + j], v, acc[i]);  // s_load
        }
        #pragma unroll
        for (int i = 0; i < ICHUNK; ++i) tmp_s[i * DDIM + tid] = acc[i];
    }
    __syncthreads();

    // h1[i,d] = relu(sum_k tmp[i,k] * W_gcn[k,d])
    {
        float acc[ICHUNK];
        #pragma unroll
        for (int i = 0; i < ICHUNK; ++i) acc[i] = 0.f;
        for (int k = 0; k < DDIM; ++k) {
            const float w = W_gcn[k * DDIM + tid];
            #pragma unroll
            for (int i = 0; i < ICHUNK; ++i)
                acc[i] = fmaf(tmp_s[i * DDIM + k], w, acc[i]);     // LDS broadcast
        }
        #pragma unroll
        for (int i = 0; i < ICHUNK; ++i) h1_s[i * DDIM + tid] = fmaxf(acc[i], 0.f);
    }
    __syncthreads();

    // out[i,o] = h1[i,:] . W_out[:,o] + b_out[o]
    if (tid < ICHUNK * 2) {
        const int i = tid >> 1;
        const int o = tid & 1;
        float acc = b_out[o];
        for (int dd = 0; dd < DDIM; ++dd)
            acc = fmaf(h1_s[i * DDIM + dd], W_out[dd * 2 + o], acc);
        out2[((size_t)b * HM_C + i0 + i) * 2 + o] = acc;
    }
}

extern "C" void kernel_launch(void* const* d_in, const int* in_sizes, int n_in,
                              void* d_out, int out_size, void* d_ws, size_t ws_size,
                              hipStream_t stream) {
    const float* hm      = (const float*)d_in[0];
    const float* feat    = (const float*)d_in[1];
    const float* W_embed = (const float*)d_in[2];
    const float* b_embed = (const float*)d_in[3];
    const float* A       = (const float*)d_in[4];
    const float* W_gcn   = (const float*)d_in[5];
    const float* W_out   = (const float*)d_in[6];
    const float* b_out   = (const float*)d_in[7];

    float* out_hm = (float*)d_out;                 // [B,C,H,W] passthrough
    float* out2   = (float*)d_out + HM_ELEMS;      // [B,C,2]

    char* ws = (char*)d_ws;
    int*   idx_ws  = (int*)ws;    ws += BC * sizeof(int);
    float* conf_ws = (float*)ws;  ws += BC * sizeof(float);
    float* h0      = (float*)ws;

    argmax_copy_kernel<<<BC, 256, 0, stream>>>(hm, out_hm, idx_ws, conf_ws);
    embed_kernel<<<BC / LCHUNK, 256, 0, stream>>>(feat, idx_ws, conf_ws,
                                                  W_embed, b_embed, h0);
    gcn_kernel<<<HM_B * (HM_C / ICHUNK), 128, 0, stream>>>(A, h0, W_gcn,
                                                           W_out, b_out, out2);
}